// Round 1
// 2253.275 us; speedup vs baseline: 3.6182x; 3.6182x over previous
//
#include <hip/hip_runtime.h>

#define NUM_USERS 50000
#define NUM_ITEMS 100000
#define N_NODES   150000
#define EMBED     64
#define BATCH     4096
#define NNZ       2400000

__device__ __forceinline__ float bf2f(unsigned short u) {
    union { unsigned int u32; float f; } v; v.u32 = ((unsigned int)u) << 16; return v.f;
}
// float input: fbf=1 -> bf16 storage, else fp32
__device__ __forceinline__ float getf(const void* p, int i, int fbf) {
    if (fbf) return bf2f(((const unsigned short*)p)[i]);
    return ((const float*)p)[i];
}
// int input: i64=1 -> int64 storage, else int32
__device__ __forceinline__ int geti(const void* p, int i, int i64) {
    if (i64) return (int)(((const long long*)p)[i]);
    return ((const int*)p)[i];
}
__device__ __forceinline__ int clampi(int v, int lo, int hi) {
    return v < lo ? lo : (v > hi ? hi : v);
}
__device__ __forceinline__ float rlane(float v, int k) {
    return __int_as_float(__builtin_amdgcn_readlane(__float_as_int(v), k));
}

// -------- dtype probes (wave-uniform flags in ws) --------
__global__ void k_flags_r12(const unsigned short* __restrict__ ev,
                            const void* __restrict__ er, int* __restrict__ fl) {
    if (threadIdx.x == 0 && blockIdx.x == 0) {
        int good = 0;
        for (int i = 0; i < 64; ++i) {
            float f = bf2f(ev[i]);
            if (f >= 0.0f && f <= 0.011f) good++;
        }
        fl[0] = (good >= 60) ? 1 : 0;   // floats stored as bf16?
        int ok = 0;
        for (int i = 0; i < 64; ++i) {
            long long v = ((const long long*)er)[i];
            if (v >= 0 && v < (long long)N_NODES) ok++;
        }
        fl[1] = (ok >= 60) ? 1 : 0;     // ints stored as int64?
    }
}

// -------- E0 = concat(embed_user, embed_item), fp32 --------
__global__ void k_init_r12(const void* __restrict__ eu, const void* __restrict__ ei,
                           const int* __restrict__ fl, float* __restrict__ E) {
    int fbf = fl[0];
    int i = blockIdx.x * 256 + threadIdx.x;
    if (i < N_NODES * EMBED) {
        int r = i >> 6;
        float v;
        if (r < NUM_USERS) v = getf(eu, i, fbf);
        else               v = getf(ei, i - NUM_USERS * EMBED, fbf);
        E[i] = v;
    }
}

// -------- LE[r] += val_e * E[c_e]  (wave per edge, lane per dim) --------
__global__ __launch_bounds__(256) void k_edge_r12(const void* __restrict__ ev,
                                                  const void* __restrict__ er,
                                                  const void* __restrict__ ec,
                                                  const int* __restrict__ fl,
                                                  const float* __restrict__ E,
                                                  float* __restrict__ LE) {
    int fbf = fl[0];
    int i64 = fl[1];
    int e = blockIdx.x * 4 + (threadIdx.x >> 6);
    int lane = threadIdx.x & 63;
    if (e >= NNZ) return;
    int r = clampi(geti(er, e, i64), 0, N_NODES - 1);
    int c = clampi(geti(ec, e, i64), 0, N_NODES - 1);
    float v = getf(ev, e, fbf);
    atomicAdd(&LE[r * EMBED + lane], v * E[c * EMBED + lane]);
}

// -------- dense layer: wave-per-row, weights in registers, readlane broadcast --------
// Enew[row] = rownorm(leaky( LE @ (W1+W2)^T + E @ W1^T + b1 + b2 ))
__global__ __launch_bounds__(256, 2) void k_mlp_r12(float* __restrict__ E,
                                                    const float* __restrict__ LE,
                                                    const void* __restrict__ W1,
                                                    const void* __restrict__ B1,
                                                    const void* __restrict__ W2,
                                                    const void* __restrict__ B2,
                                                    const int* __restrict__ fl, int layer) {
    const int fbf  = fl[0];
    const int wofs = layer * EMBED * EMBED;
    const int bofs = layer * EMBED;
    const int lane = threadIdx.x & 63;

    // per-thread weight registers: w1r[k] = W1[lane,k]; w12r[k] = W1[lane,k]+W2[lane,k]
    float w1r[64], w12r[64];
    if (fbf) {
        const unsigned short* p1 = (const unsigned short*)W1 + wofs + lane * 64;
        const unsigned short* p2 = (const unsigned short*)W2 + wofs + lane * 64;
        #pragma unroll
        for (int q = 0; q < 16; ++q) {
            ushort4 a = reinterpret_cast<const ushort4*>(p1)[q];
            ushort4 b = reinterpret_cast<const ushort4*>(p2)[q];
            float f0 = bf2f(a.x), f1 = bf2f(a.y), f2 = bf2f(a.z), f3 = bf2f(a.w);
            w1r[4*q+0] = f0; w1r[4*q+1] = f1; w1r[4*q+2] = f2; w1r[4*q+3] = f3;
            w12r[4*q+0] = f0 + bf2f(b.x); w12r[4*q+1] = f1 + bf2f(b.y);
            w12r[4*q+2] = f2 + bf2f(b.z); w12r[4*q+3] = f3 + bf2f(b.w);
        }
    } else {
        const float* p1 = (const float*)W1 + wofs + lane * 64;
        const float* p2 = (const float*)W2 + wofs + lane * 64;
        #pragma unroll
        for (int q = 0; q < 16; ++q) {
            float4 a = reinterpret_cast<const float4*>(p1)[q];
            float4 b = reinterpret_cast<const float4*>(p2)[q];
            w1r[4*q+0] = a.x; w1r[4*q+1] = a.y; w1r[4*q+2] = a.z; w1r[4*q+3] = a.w;
            w12r[4*q+0] = a.x + b.x; w12r[4*q+1] = a.y + b.y;
            w12r[4*q+2] = a.z + b.z; w12r[4*q+3] = a.w + b.w;
        }
    }
    const float bias = getf(B1, bofs + lane, fbf) + getf(B2, bofs + lane, fbf);

    const int gw = blockIdx.x * 4 + (threadIdx.x >> 6);   // global wave id
    const int nw = gridDim.x * 4;                          // total waves

    int row = gw;
    float le = 0.0f, ee = 0.0f;
    if (row < N_NODES) {
        le = LE[row * EMBED + lane];
        ee = E[row * EMBED + lane];
    }
    while (row < N_NODES) {
        // software prefetch next row (issued before the FMA chain + store)
        const int nrow = row + nw;
        float nle = 0.0f, nee = 0.0f;
        if (nrow < N_NODES) {
            nle = LE[nrow * EMBED + lane];
            nee = E[nrow * EMBED + lane];
        }

        float acc = bias;
        #pragma unroll
        for (int k = 0; k < 64; ++k) {
            acc = fmaf(rlane(le, k), w12r[k], fmaf(rlane(ee, k), w1r[k], acc));
        }
        float h = (acc > 0.0f) ? acc : 0.2f * acc;

        // wave-level row-norm reduction (all 64 lanes = the row)
        float s = h * h;
        #pragma unroll
        for (int d = 1; d < 64; d <<= 1) s += __shfl_xor(s, d, 64);
        const float inv = 1.0f / fmaxf(sqrtf(s), 1e-12f);

        E[row * EMBED + lane] = h * inv;

        row = nrow; le = nle; ee = nee;
    }
}

// -------- gather batch rows into FLOAT output, column slice [stage*64, +64) --------
__global__ void k_pick_r12(const float* __restrict__ E, const void* __restrict__ bu,
                           const void* __restrict__ bp, const void* __restrict__ bn,
                           const int* __restrict__ fl,
                           float* __restrict__ out, int stage) {
    int i64 = fl[1];
    int i = blockIdx.x * 256 + threadIdx.x;
    if (i >= 3 * BATCH * EMBED) return;
    int c = i & 63;
    int row = i >> 6;
    int o = row >> 12;       // output tensor 0/1/2
    int b = row & 4095;      // row within batch
    int idx;
    if (o == 0)      idx = geti(bu, b, i64);
    else if (o == 1) idx = geti(bp, b, i64);
    else             idx = geti(bn, b, i64);
    int src;
    if (o == 0) src = clampi(idx, 0, NUM_USERS - 1);
    else        src = NUM_USERS + clampi(idx, 0, NUM_ITEMS - 1);
    int pos = o * (BATCH * 256) + b * 256 + stage * 64 + c;
    out[pos] = E[src * EMBED + c];
}

// -------- launch --------
extern "C" void kernel_launch(void* const* d_in, const int* in_sizes, int n_in,
                              void* d_out, int out_size, void* d_ws, size_t ws_size,
                              hipStream_t stream) {
    const void* edge_val = d_in[0];
    const void* emb_u    = d_in[1];
    const void* emb_i    = d_in[2];
    const void* W1w      = d_in[3];
    const void* W1b      = d_in[4];
    const void* W2w      = d_in[5];
    const void* W2b      = d_in[6];
    const void* erow     = d_in[7];
    const void* ecol     = d_in[8];
    const void* bu       = d_in[9];
    const void* bp       = d_in[10];
    const void* bn       = d_in[11];

    const size_t EB = (size_t)N_NODES * EMBED * sizeof(float);   // 38.4 MB
    const size_t need = 256 + 2 * EB;
    if (ws_size < need) return;   // zero-output signature if ws too small

    char* ws = (char*)d_ws;
    int*   fl = (int*)ws;
    float* E  = (float*)(ws + 256);
    float* LE = (float*)(ws + 256 + EB);
    float* out = (float*)d_out;

    k_flags_r12<<<1, 64, 0, stream>>>((const unsigned short*)edge_val, erow, fl);

    k_init_r12<<<(N_NODES * EMBED + 255) / 256, 256, 0, stream>>>(emb_u, emb_i, fl, E);

    k_pick_r12<<<(3 * BATCH * EMBED + 255) / 256, 256, 0, stream>>>(E, bu, bp, bn, fl, out, 0);

    for (int l = 0; l < 3; ++l) {
        hipMemsetAsync(LE, 0, EB, stream);
        k_edge_r12<<<(NNZ + 3) / 4, 256, 0, stream>>>(edge_val, erow, ecol, fl, E, LE);
        k_mlp_r12<<<768, 256, 0, stream>>>(E, LE, W1w, W1b, W2w, W2b, fl, l);
        k_pick_r12<<<(3 * BATCH * EMBED + 255) / 256, 256, 0, stream>>>(E, bu, bp, bn, fl, out, l + 1);
    }
}

// Round 2
// 1213.149 us; speedup vs baseline: 6.7204x; 1.8574x over previous
//
#include <hip/hip_runtime.h>

#define NUM_USERS 50000
#define NUM_ITEMS 100000
#define N_NODES   150000
#define EMBED     64
#define BATCH     4096
#define NNZ       2400000
#define NB        586   // ceil(N_NODES/256)

__device__ __forceinline__ float bf2f(unsigned short u) {
    union { unsigned int u32; float f; } v; v.u32 = ((unsigned int)u) << 16; return v.f;
}
__device__ __forceinline__ float getf(const void* p, int i, int fbf) {
    if (fbf) return bf2f(((const unsigned short*)p)[i]);
    return ((const float*)p)[i];
}
__device__ __forceinline__ int geti(const void* p, int i, int i64) {
    if (i64) return (int)(((const long long*)p)[i]);
    return ((const int*)p)[i];
}
__device__ __forceinline__ int clampi(int v, int lo, int hi) {
    return v < lo ? lo : (v > hi ? hi : v);
}
__device__ __forceinline__ float rlanef(float v, int k) {
    return __int_as_float(__builtin_amdgcn_readlane(__float_as_int(v), k));
}
__device__ __forceinline__ int rlanei(int v, int k) {
    return __builtin_amdgcn_readlane(v, k);
}

// -------- dtype probes --------
__global__ void k_flags_r13(const unsigned short* __restrict__ ev,
                            const void* __restrict__ er, int* __restrict__ fl) {
    if (threadIdx.x == 0 && blockIdx.x == 0) {
        int good = 0;
        for (int i = 0; i < 64; ++i) {
            float f = bf2f(ev[i]);
            if (f >= 0.0f && f <= 0.011f) good++;
        }
        fl[0] = (good >= 60) ? 1 : 0;
        int ok = 0;
        for (int i = 0; i < 64; ++i) {
            long long v = ((const long long*)er)[i];
            if (v >= 0 && v < (long long)N_NODES) ok++;
        }
        fl[1] = (ok >= 60) ? 1 : 0;
    }
}

// -------- E0 = concat --------
__global__ void k_init_r13(const void* __restrict__ eu, const void* __restrict__ ei,
                           const int* __restrict__ fl, float* __restrict__ E) {
    int fbf = fl[0];
    int i = blockIdx.x * 256 + threadIdx.x;
    if (i < N_NODES * EMBED) {
        int r = i >> 6;
        float v;
        if (r < NUM_USERS) v = getf(eu, i, fbf);
        else               v = getf(ei, i - NUM_USERS * EMBED, fbf);
        E[i] = v;
    }
}

// ============ CSR build ============
__global__ __launch_bounds__(256) void k_count_r13(const void* __restrict__ er,
                                                   const int* __restrict__ fl,
                                                   int* __restrict__ cnt) {
    int e = blockIdx.x * 256 + threadIdx.x;
    if (e >= NNZ) return;
    int r = clampi(geti(er, e, fl[1]), 0, N_NODES - 1);
    atomicAdd(&cnt[r], 1);
}

// block sums of cnt (256 per block)
__global__ __launch_bounds__(256) void k_scanA_r13(const int* __restrict__ cnt,
                                                   int* __restrict__ bsum) {
    int i = blockIdx.x * 256 + threadIdx.x;
    int v = (i < N_NODES) ? cnt[i] : 0;
    #pragma unroll
    for (int d = 1; d < 64; d <<= 1) v += __shfl_xor(v, d, 64);
    __shared__ int sh[4];
    if ((threadIdx.x & 63) == 0) sh[threadIdx.x >> 6] = v;
    __syncthreads();
    if (threadIdx.x == 0) bsum[blockIdx.x] = sh[0] + sh[1] + sh[2] + sh[3];
}

// exclusive scan of NB block sums (single block)
__global__ __launch_bounds__(1024) void k_scanB_r13(int* __restrict__ bsum) {
    __shared__ int sh[1024];
    int t = threadIdx.x;
    if (t < NB) sh[t] = bsum[t];
    __syncthreads();
    if (t == 0) {
        int run = 0;
        for (int i = 0; i < NB; ++i) { int x = sh[i]; sh[i] = run; run += x; }
    }
    __syncthreads();
    if (t < NB) bsum[t] = sh[t];
}

// final exclusive scan: rowptr[i] = bsum[b] + excl-scan within block
__global__ __launch_bounds__(256) void k_scanC_r13(const int* __restrict__ cnt,
                                                   const int* __restrict__ bsum,
                                                   int* __restrict__ rowptr) {
    __shared__ int sh[256];
    int i = blockIdx.x * 256 + threadIdx.x;
    int t = threadIdx.x;
    sh[t] = (i < N_NODES) ? cnt[i] : 0;
    __syncthreads();
    if (t == 0) {
        int run = bsum[blockIdx.x];
        for (int k = 0; k < 256; ++k) { int x = sh[k]; sh[k] = run; run += x; }
    }
    __syncthreads();
    if (i < N_NODES) rowptr[i] = sh[t];
    if (i == 0) rowptr[N_NODES] = NNZ;
}

// scatter edges into CSR slots (cur[] pre-zeroed)
__global__ __launch_bounds__(256) void k_scatter_r13(const void* __restrict__ ev,
                                                     const void* __restrict__ er,
                                                     const void* __restrict__ ec,
                                                     const int* __restrict__ fl,
                                                     const int* __restrict__ rowptr,
                                                     int* __restrict__ cur,
                                                     int* __restrict__ colc,
                                                     float* __restrict__ colval) {
    int e = blockIdx.x * 256 + threadIdx.x;
    if (e >= NNZ) return;
    int i64 = fl[1], fbf = fl[0];
    int r = clampi(geti(er, e, i64), 0, N_NODES - 1);
    int c = clampi(geti(ec, e, i64), 0, N_NODES - 1);
    float v = getf(ev, e, fbf);
    int p = rowptr[r] + atomicAdd(&cur[r], 1);
    colc[p] = c;
    colval[p] = v;
}

// ============ gather: LE[r] = sum_e val * E[col], wave per row, no atomics ============
__global__ __launch_bounds__(256) void k_gath_r13(const int* __restrict__ rowptr,
                                                  const int* __restrict__ colc,
                                                  const float* __restrict__ colval,
                                                  const float* __restrict__ E,
                                                  float* __restrict__ LE) {
    int r = blockIdx.x * 4 + (threadIdx.x >> 6);
    if (r >= N_NODES) return;
    int lane = threadIdx.x & 63;
    int s = rowptr[r];
    int e = rowptr[r + 1];
    float acc = 0.0f;
    for (int base = s; base < e; base += 64) {
        int idx = base + lane;
        int c = 0; float v = 0.0f;
        if (idx < e) { c = colc[idx]; v = colval[idx]; }
        int m = e - base; if (m > 64) m = 64;
        for (int j = 0; j < m; ++j) {
            int cj = rlanei(c, j);
            float vj = rlanef(v, j);
            acc = fmaf(vj, E[cj * EMBED + lane], acc);
        }
    }
    LE[r * EMBED + lane] = acc;
}

// -------- fallback atomic edge pass (small-ws path) --------
__global__ __launch_bounds__(256) void k_edge_r13(const void* __restrict__ ev,
                                                  const void* __restrict__ er,
                                                  const void* __restrict__ ec,
                                                  const int* __restrict__ fl,
                                                  const float* __restrict__ E,
                                                  float* __restrict__ LE) {
    int fbf = fl[0];
    int i64 = fl[1];
    int e = blockIdx.x * 4 + (threadIdx.x >> 6);
    int lane = threadIdx.x & 63;
    if (e >= NNZ) return;
    int r = clampi(geti(er, e, i64), 0, N_NODES - 1);
    int c = clampi(geti(ec, e, i64), 0, N_NODES - 1);
    float v = getf(ev, e, fbf);
    atomicAdd(&LE[r * EMBED + lane], v * E[c * EMBED + lane]);
}

// -------- dense layer: wave-per-row, weights in registers, readlane broadcast --------
__global__ __launch_bounds__(256, 2) void k_mlp_r13(float* __restrict__ E,
                                                    const float* __restrict__ LE,
                                                    const void* __restrict__ W1,
                                                    const void* __restrict__ B1,
                                                    const void* __restrict__ W2,
                                                    const void* __restrict__ B2,
                                                    const int* __restrict__ fl, int layer) {
    const int fbf  = fl[0];
    const int wofs = layer * EMBED * EMBED;
    const int bofs = layer * EMBED;
    const int lane = threadIdx.x & 63;

    float w1r[64], w12r[64];
    if (fbf) {
        const unsigned short* p1 = (const unsigned short*)W1 + wofs + lane * 64;
        const unsigned short* p2 = (const unsigned short*)W2 + wofs + lane * 64;
        #pragma unroll
        for (int q = 0; q < 16; ++q) {
            ushort4 a = reinterpret_cast<const ushort4*>(p1)[q];
            ushort4 b = reinterpret_cast<const ushort4*>(p2)[q];
            float f0 = bf2f(a.x), f1 = bf2f(a.y), f2 = bf2f(a.z), f3 = bf2f(a.w);
            w1r[4*q+0] = f0; w1r[4*q+1] = f1; w1r[4*q+2] = f2; w1r[4*q+3] = f3;
            w12r[4*q+0] = f0 + bf2f(b.x); w12r[4*q+1] = f1 + bf2f(b.y);
            w12r[4*q+2] = f2 + bf2f(b.z); w12r[4*q+3] = f3 + bf2f(b.w);
        }
    } else {
        const float* p1 = (const float*)W1 + wofs + lane * 64;
        const float* p2 = (const float*)W2 + wofs + lane * 64;
        #pragma unroll
        for (int q = 0; q < 16; ++q) {
            float4 a = reinterpret_cast<const float4*>(p1)[q];
            float4 b = reinterpret_cast<const float4*>(p2)[q];
            w1r[4*q+0] = a.x; w1r[4*q+1] = a.y; w1r[4*q+2] = a.z; w1r[4*q+3] = a.w;
            w12r[4*q+0] = a.x + b.x; w12r[4*q+1] = a.y + b.y;
            w12r[4*q+2] = a.z + b.z; w12r[4*q+3] = a.w + b.w;
        }
    }
    const float bias = getf(B1, bofs + lane, fbf) + getf(B2, bofs + lane, fbf);

    const int gw = blockIdx.x * 4 + (threadIdx.x >> 6);
    const int nw = gridDim.x * 4;

    int row = gw;
    float le = 0.0f, ee = 0.0f;
    if (row < N_NODES) {
        le = LE[row * EMBED + lane];
        ee = E[row * EMBED + lane];
    }
    while (row < N_NODES) {
        const int nrow = row + nw;
        float nle = 0.0f, nee = 0.0f;
        if (nrow < N_NODES) {
            nle = LE[nrow * EMBED + lane];
            nee = E[nrow * EMBED + lane];
        }

        float acc = bias;
        #pragma unroll
        for (int k = 0; k < 64; ++k) {
            acc = fmaf(rlanef(le, k), w12r[k], fmaf(rlanef(ee, k), w1r[k], acc));
        }
        float h = (acc > 0.0f) ? acc : 0.2f * acc;

        float s = h * h;
        #pragma unroll
        for (int d = 1; d < 64; d <<= 1) s += __shfl_xor(s, d, 64);
        const float inv = 1.0f / fmaxf(sqrtf(s), 1e-12f);

        E[row * EMBED + lane] = h * inv;

        row = nrow; le = nle; ee = nee;
    }
}

// -------- gather batch rows into output --------
__global__ void k_pick_r13(const float* __restrict__ E, const void* __restrict__ bu,
                           const void* __restrict__ bp, const void* __restrict__ bn,
                           const int* __restrict__ fl,
                           float* __restrict__ out, int stage) {
    int i64 = fl[1];
    int i = blockIdx.x * 256 + threadIdx.x;
    if (i >= 3 * BATCH * EMBED) return;
    int c = i & 63;
    int row = i >> 6;
    int o = row >> 12;
    int b = row & 4095;
    int idx;
    if (o == 0)      idx = geti(bu, b, i64);
    else if (o == 1) idx = geti(bp, b, i64);
    else             idx = geti(bn, b, i64);
    int src;
    if (o == 0) src = clampi(idx, 0, NUM_USERS - 1);
    else        src = NUM_USERS + clampi(idx, 0, NUM_ITEMS - 1);
    int pos = o * (BATCH * 256) + b * 256 + stage * 64 + c;
    out[pos] = E[src * EMBED + c];
}

// -------- launch --------
extern "C" void kernel_launch(void* const* d_in, const int* in_sizes, int n_in,
                              void* d_out, int out_size, void* d_ws, size_t ws_size,
                              hipStream_t stream) {
    const void* edge_val = d_in[0];
    const void* emb_u    = d_in[1];
    const void* emb_i    = d_in[2];
    const void* W1w      = d_in[3];
    const void* W1b      = d_in[4];
    const void* W2w      = d_in[5];
    const void* W2b      = d_in[6];
    const void* erow     = d_in[7];
    const void* ecol     = d_in[8];
    const void* bu       = d_in[9];
    const void* bp       = d_in[10];
    const void* bn       = d_in[11];

    const size_t EB   = (size_t)N_NODES * EMBED * sizeof(float);   // 38.4 MB
    const size_t RPB  = 600064;                                     // rowptr (150001 ints, padded)
    const size_t CNB  = 600064;                                     // cnt/cursor
    const size_t BSB  = 4096;                                       // block sums
    const size_t CCB  = (size_t)NNZ * sizeof(int);                  // 9.6 MB colc
    const size_t CVB  = (size_t)NNZ * sizeof(float);                // 9.6 MB colval

    const size_t need_old = 256 + 2 * EB;
    const size_t need_csr = 256 + 2 * EB + RPB + CNB + BSB + CCB + CVB;
    if (ws_size < need_old) return;   // zero-output signature

    char* ws = (char*)d_ws;
    int*   fl     = (int*)ws;
    float* E      = (float*)(ws + 256);
    float* LE     = (float*)(ws + 256 + EB);
    int*   rowptr = (int*)(ws + 256 + 2 * EB);
    int*   cnt    = (int*)(ws + 256 + 2 * EB + RPB);
    int*   bsum   = (int*)(ws + 256 + 2 * EB + RPB + CNB);
    int*   colc   = (int*)(ws + 256 + 2 * EB + RPB + CNB + BSB);
    float* colval = (float*)(ws + 256 + 2 * EB + RPB + CNB + BSB + CCB);
    float* out    = (float*)d_out;

    const bool use_csr = (ws_size >= need_csr);

    k_flags_r13<<<1, 64, 0, stream>>>((const unsigned short*)edge_val, erow, fl);

    k_init_r13<<<(N_NODES * EMBED + 255) / 256, 256, 0, stream>>>(emb_u, emb_i, fl, E);

    if (use_csr) {
        hipMemsetAsync(cnt, 0, CNB, stream);
        k_count_r13<<<(NNZ + 255) / 256, 256, 0, stream>>>(erow, fl, cnt);
        k_scanA_r13<<<NB, 256, 0, stream>>>(cnt, bsum);
        k_scanB_r13<<<1, 1024, 0, stream>>>(bsum);
        k_scanC_r13<<<NB, 256, 0, stream>>>(cnt, bsum, rowptr);
        hipMemsetAsync(cnt, 0, CNB, stream);
        k_scatter_r13<<<(NNZ + 255) / 256, 256, 0, stream>>>(edge_val, erow, ecol, fl,
                                                             rowptr, cnt, colc, colval);
    }

    k_pick_r13<<<(3 * BATCH * EMBED + 255) / 256, 256, 0, stream>>>(E, bu, bp, bn, fl, out, 0);

    for (int l = 0; l < 3; ++l) {
        if (use_csr) {
            k_gath_r13<<<(N_NODES + 3) / 4, 256, 0, stream>>>(rowptr, colc, colval, E, LE);
        } else {
            hipMemsetAsync(LE, 0, EB, stream);
            k_edge_r13<<<(NNZ + 3) / 4, 256, 0, stream>>>(edge_val, erow, ecol, fl, E, LE);
        }
        k_mlp_r13<<<768, 256, 0, stream>>>(E, LE, W1w, W1b, W2w, W2b, fl, l);
        k_pick_r13<<<(3 * BATCH * EMBED + 255) / 256, 256, 0, stream>>>(E, bu, bp, bn, fl, out, l + 1);
    }
}

// Round 3
// 1019.321 us; speedup vs baseline: 7.9984x; 1.1902x over previous
//
#include <hip/hip_runtime.h>

#define NUM_USERS 50000
#define NUM_ITEMS 100000
#define N_NODES   150000
#define EMBED     64
#define BATCH     4096
#define NNZ       2400000
#define NB        586   // ceil(N_NODES/256)

__device__ __forceinline__ float bf2f(unsigned short u) {
    union { unsigned int u32; float f; } v; v.u32 = ((unsigned int)u) << 16; return v.f;
}
__device__ __forceinline__ float getf(const void* p, int i, int fbf) {
    if (fbf) return bf2f(((const unsigned short*)p)[i]);
    return ((const float*)p)[i];
}
__device__ __forceinline__ int geti(const void* p, int i, int i64) {
    if (i64) return (int)(((const long long*)p)[i]);
    return ((const int*)p)[i];
}
__device__ __forceinline__ int clampi(int v, int lo, int hi) {
    return v < lo ? lo : (v > hi ? hi : v);
}
__device__ __forceinline__ float rlanef(float v, int k) {
    return __int_as_float(__builtin_amdgcn_readlane(__float_as_int(v), k));
}
__device__ __forceinline__ int rlanei(int v, int k) {
    return __builtin_amdgcn_readlane(v, k);
}

// -------- dtype probes --------
__global__ void k_flags_r14(const unsigned short* __restrict__ ev,
                            const void* __restrict__ er, int* __restrict__ fl) {
    if (threadIdx.x == 0 && blockIdx.x == 0) {
        int good = 0;
        for (int i = 0; i < 64; ++i) {
            float f = bf2f(ev[i]);
            if (f >= 0.0f && f <= 0.011f) good++;
        }
        fl[0] = (good >= 60) ? 1 : 0;
        int ok = 0;
        for (int i = 0; i < 64; ++i) {
            long long v = ((const long long*)er)[i];
            if (v >= 0 && v < (long long)N_NODES) ok++;
        }
        fl[1] = (ok >= 60) ? 1 : 0;
    }
}

// -------- E0 = concat --------
__global__ void k_init_r14(const void* __restrict__ eu, const void* __restrict__ ei,
                           const int* __restrict__ fl, float* __restrict__ E) {
    int fbf = fl[0];
    int i = blockIdx.x * 256 + threadIdx.x;
    if (i < N_NODES * EMBED) {
        int r = i >> 6;
        float v;
        if (r < NUM_USERS) v = getf(eu, i, fbf);
        else               v = getf(ei, i - NUM_USERS * EMBED, fbf);
        E[i] = v;
    }
}

// ============ CSR build ============
__global__ __launch_bounds__(256) void k_count_r14(const void* __restrict__ er,
                                                   const int* __restrict__ fl,
                                                   int* __restrict__ cnt) {
    int e = blockIdx.x * 256 + threadIdx.x;
    if (e >= NNZ) return;
    int r = clampi(geti(er, e, fl[1]), 0, N_NODES - 1);
    atomicAdd(&cnt[r], 1);
}

__global__ __launch_bounds__(256) void k_scanA_r14(const int* __restrict__ cnt,
                                                   int* __restrict__ bsum) {
    int i = blockIdx.x * 256 + threadIdx.x;
    int v = (i < N_NODES) ? cnt[i] : 0;
    #pragma unroll
    for (int d = 1; d < 64; d <<= 1) v += __shfl_xor(v, d, 64);
    __shared__ int sh[4];
    if ((threadIdx.x & 63) == 0) sh[threadIdx.x >> 6] = v;
    __syncthreads();
    if (threadIdx.x == 0) bsum[blockIdx.x] = sh[0] + sh[1] + sh[2] + sh[3];
}

__global__ __launch_bounds__(1024) void k_scanB_r14(int* __restrict__ bsum) {
    __shared__ int sh[1024];
    int t = threadIdx.x;
    if (t < NB) sh[t] = bsum[t];
    __syncthreads();
    if (t == 0) {
        int run = 0;
        for (int i = 0; i < NB; ++i) { int x = sh[i]; sh[i] = run; run += x; }
    }
    __syncthreads();
    if (t < NB) bsum[t] = sh[t];
}

__global__ __launch_bounds__(256) void k_scanC_r14(const int* __restrict__ cnt,
                                                   const int* __restrict__ bsum,
                                                   int* __restrict__ rowptr) {
    __shared__ int sh[256];
    int i = blockIdx.x * 256 + threadIdx.x;
    int t = threadIdx.x;
    sh[t] = (i < N_NODES) ? cnt[i] : 0;
    __syncthreads();
    if (t == 0) {
        int run = bsum[blockIdx.x];
        for (int k = 0; k < 256; ++k) { int x = sh[k]; sh[k] = run; run += x; }
    }
    __syncthreads();
    if (i < N_NODES) rowptr[i] = sh[t];
    if (i == 0) rowptr[N_NODES] = NNZ;
}

// scatter edges into CSR slots — PACKED int2 {col, val_bits}: one 8B store/edge
__global__ __launch_bounds__(256) void k_scatter_r14(const void* __restrict__ ev,
                                                     const void* __restrict__ er,
                                                     const void* __restrict__ ec,
                                                     const int* __restrict__ fl,
                                                     const int* __restrict__ rowptr,
                                                     int* __restrict__ cur,
                                                     int2* __restrict__ colcv) {
    int e = blockIdx.x * 256 + threadIdx.x;
    if (e >= NNZ) return;
    int i64 = fl[1], fbf = fl[0];
    int r = clampi(geti(er, e, i64), 0, N_NODES - 1);
    int c = clampi(geti(ec, e, i64), 0, N_NODES - 1);
    float v = getf(ev, e, fbf);
    int p = rowptr[r] + atomicAdd(&cur[r], 1);
    colcv[p] = make_int2(c, __float_as_int(v));
}

// ============ gather: LE[r] = sum val*E[col], wave/row, 4-deep load pipeline ============
__global__ __launch_bounds__(256) void k_gath_r14(const int* __restrict__ rowptr,
                                                  const int2* __restrict__ colcv,
                                                  const float* __restrict__ E,
                                                  float* __restrict__ LE) {
    int r = blockIdx.x * 4 + (threadIdx.x >> 6);
    if (r >= N_NODES) return;
    int lane = threadIdx.x & 63;
    int s = rowptr[r];
    int e = rowptr[r + 1];
    float acc = 0.0f;
    for (int base = s; base < e; base += 64) {
        int idx = base + lane;
        int2 cv = make_int2(0, 0);
        if (idx < e) cv = colcv[idx];
        int m = e - base; if (m > 64) m = 64;
        int j = 0;
        for (; j + 3 < m; j += 4) {
            int c0 = rlanei(cv.x, j + 0);
            int c1 = rlanei(cv.x, j + 1);
            int c2 = rlanei(cv.x, j + 2);
            int c3 = rlanei(cv.x, j + 3);
            // 4 independent coalesced row loads issued before any use
            float p0 = E[c0 * EMBED + lane];
            float p1 = E[c1 * EMBED + lane];
            float p2 = E[c2 * EMBED + lane];
            float p3 = E[c3 * EMBED + lane];
            float v0 = __int_as_float(rlanei(cv.y, j + 0));
            float v1 = __int_as_float(rlanei(cv.y, j + 1));
            float v2 = __int_as_float(rlanei(cv.y, j + 2));
            float v3 = __int_as_float(rlanei(cv.y, j + 3));
            acc = fmaf(v0, p0, acc);
            acc = fmaf(v1, p1, acc);
            acc = fmaf(v2, p2, acc);
            acc = fmaf(v3, p3, acc);
        }
        for (; j < m; ++j) {
            int cj = rlanei(cv.x, j);
            float vj = __int_as_float(rlanei(cv.y, j));
            acc = fmaf(vj, E[cj * EMBED + lane], acc);
        }
    }
    LE[r * EMBED + lane] = acc;
}

// -------- fallback atomic edge pass (small-ws path) --------
__global__ __launch_bounds__(256) void k_edge_r14(const void* __restrict__ ev,
                                                  const void* __restrict__ er,
                                                  const void* __restrict__ ec,
                                                  const int* __restrict__ fl,
                                                  const float* __restrict__ E,
                                                  float* __restrict__ LE) {
    int fbf = fl[0];
    int i64 = fl[1];
    int e = blockIdx.x * 4 + (threadIdx.x >> 6);
    int lane = threadIdx.x & 63;
    if (e >= NNZ) return;
    int r = clampi(geti(er, e, i64), 0, N_NODES - 1);
    int c = clampi(geti(ec, e, i64), 0, N_NODES - 1);
    float v = getf(ev, e, fbf);
    atomicAdd(&LE[r * EMBED + lane], v * E[c * EMBED + lane]);
}

// -------- dense layer: wave-per-row, weights in registers, readlane broadcast --------
__global__ __launch_bounds__(256, 2) void k_mlp_r14(float* __restrict__ E,
                                                    const float* __restrict__ LE,
                                                    const void* __restrict__ W1,
                                                    const void* __restrict__ B1,
                                                    const void* __restrict__ W2,
                                                    const void* __restrict__ B2,
                                                    const int* __restrict__ fl, int layer) {
    const int fbf  = fl[0];
    const int wofs = layer * EMBED * EMBED;
    const int bofs = layer * EMBED;
    const int lane = threadIdx.x & 63;

    float w1r[64], w12r[64];
    if (fbf) {
        const unsigned short* p1 = (const unsigned short*)W1 + wofs + lane * 64;
        const unsigned short* p2 = (const unsigned short*)W2 + wofs + lane * 64;
        #pragma unroll
        for (int q = 0; q < 16; ++q) {
            ushort4 a = reinterpret_cast<const ushort4*>(p1)[q];
            ushort4 b = reinterpret_cast<const ushort4*>(p2)[q];
            float f0 = bf2f(a.x), f1 = bf2f(a.y), f2 = bf2f(a.z), f3 = bf2f(a.w);
            w1r[4*q+0] = f0; w1r[4*q+1] = f1; w1r[4*q+2] = f2; w1r[4*q+3] = f3;
            w12r[4*q+0] = f0 + bf2f(b.x); w12r[4*q+1] = f1 + bf2f(b.y);
            w12r[4*q+2] = f2 + bf2f(b.z); w12r[4*q+3] = f3 + bf2f(b.w);
        }
    } else {
        const float* p1 = (const float*)W1 + wofs + lane * 64;
        const float* p2 = (const float*)W2 + wofs + lane * 64;
        #pragma unroll
        for (int q = 0; q < 16; ++q) {
            float4 a = reinterpret_cast<const float4*>(p1)[q];
            float4 b = reinterpret_cast<const float4*>(p2)[q];
            w1r[4*q+0] = a.x; w1r[4*q+1] = a.y; w1r[4*q+2] = a.z; w1r[4*q+3] = a.w;
            w12r[4*q+0] = a.x + b.x; w12r[4*q+1] = a.y + b.y;
            w12r[4*q+2] = a.z + b.z; w12r[4*q+3] = a.w + b.w;
        }
    }
    const float bias = getf(B1, bofs + lane, fbf) + getf(B2, bofs + lane, fbf);

    const int gw = blockIdx.x * 4 + (threadIdx.x >> 6);
    const int nw = gridDim.x * 4;

    int row = gw;
    float le = 0.0f, ee = 0.0f;
    if (row < N_NODES) {
        le = LE[row * EMBED + lane];
        ee = E[row * EMBED + lane];
    }
    while (row < N_NODES) {
        const int nrow = row + nw;
        float nle = 0.0f, nee = 0.0f;
        if (nrow < N_NODES) {
            nle = LE[nrow * EMBED + lane];
            nee = E[nrow * EMBED + lane];
        }

        float acc = bias;
        #pragma unroll
        for (int k = 0; k < 64; ++k) {
            acc = fmaf(rlanef(le, k), w12r[k], fmaf(rlanef(ee, k), w1r[k], acc));
        }
        float h = (acc > 0.0f) ? acc : 0.2f * acc;

        float s = h * h;
        #pragma unroll
        for (int d = 1; d < 64; d <<= 1) s += __shfl_xor(s, d, 64);
        const float inv = 1.0f / fmaxf(sqrtf(s), 1e-12f);

        E[row * EMBED + lane] = h * inv;

        row = nrow; le = nle; ee = nee;
    }
}

// -------- gather batch rows into output --------
__global__ void k_pick_r14(const float* __restrict__ E, const void* __restrict__ bu,
                           const void* __restrict__ bp, const void* __restrict__ bn,
                           const int* __restrict__ fl,
                           float* __restrict__ out, int stage) {
    int i64 = fl[1];
    int i = blockIdx.x * 256 + threadIdx.x;
    if (i >= 3 * BATCH * EMBED) return;
    int c = i & 63;
    int row = i >> 6;
    int o = row >> 12;
    int b = row & 4095;
    int idx;
    if (o == 0)      idx = geti(bu, b, i64);
    else if (o == 1) idx = geti(bp, b, i64);
    else             idx = geti(bn, b, i64);
    int src;
    if (o == 0) src = clampi(idx, 0, NUM_USERS - 1);
    else        src = NUM_USERS + clampi(idx, 0, NUM_ITEMS - 1);
    int pos = o * (BATCH * 256) + b * 256 + stage * 64 + c;
    out[pos] = E[src * EMBED + c];
}

// -------- launch --------
extern "C" void kernel_launch(void* const* d_in, const int* in_sizes, int n_in,
                              void* d_out, int out_size, void* d_ws, size_t ws_size,
                              hipStream_t stream) {
    const void* edge_val = d_in[0];
    const void* emb_u    = d_in[1];
    const void* emb_i    = d_in[2];
    const void* W1w      = d_in[3];
    const void* W1b      = d_in[4];
    const void* W2w      = d_in[5];
    const void* W2b      = d_in[6];
    const void* erow     = d_in[7];
    const void* ecol     = d_in[8];
    const void* bu       = d_in[9];
    const void* bp       = d_in[10];
    const void* bn       = d_in[11];

    const size_t EB   = (size_t)N_NODES * EMBED * sizeof(float);   // 38.4 MB
    const size_t RPB  = 600064;                                     // rowptr
    const size_t CNB  = 600064;                                     // cnt/cursor
    const size_t BSB  = 4096;                                       // block sums
    const size_t CVB2 = (size_t)NNZ * sizeof(int2);                 // 19.2 MB packed (c,v)

    const size_t need_old = 256 + 2 * EB;
    const size_t need_csr = 256 + 2 * EB + RPB + CNB + BSB + CVB2;
    if (ws_size < need_old) return;   // zero-output signature

    char* ws = (char*)d_ws;
    int*   fl     = (int*)ws;
    float* E      = (float*)(ws + 256);
    float* LE     = (float*)(ws + 256 + EB);
    int*   rowptr = (int*)(ws + 256 + 2 * EB);
    int*   cnt    = (int*)(ws + 256 + 2 * EB + RPB);
    int*   bsum   = (int*)(ws + 256 + 2 * EB + RPB + CNB);
    int2*  colcv  = (int2*)(ws + 256 + 2 * EB + RPB + CNB + BSB);
    float* out    = (float*)d_out;

    const bool use_csr = (ws_size >= need_csr);

    k_flags_r14<<<1, 64, 0, stream>>>((const unsigned short*)edge_val, erow, fl);

    k_init_r14<<<(N_NODES * EMBED + 255) / 256, 256, 0, stream>>>(emb_u, emb_i, fl, E);

    if (use_csr) {
        hipMemsetAsync(cnt, 0, CNB, stream);
        k_count_r14<<<(NNZ + 255) / 256, 256, 0, stream>>>(erow, fl, cnt);
        k_scanA_r14<<<NB, 256, 0, stream>>>(cnt, bsum);
        k_scanB_r14<<<1, 1024, 0, stream>>>(bsum);
        k_scanC_r14<<<NB, 256, 0, stream>>>(cnt, bsum, rowptr);
        hipMemsetAsync(cnt, 0, CNB, stream);
        k_scatter_r14<<<(NNZ + 255) / 256, 256, 0, stream>>>(edge_val, erow, ecol, fl,
                                                             rowptr, cnt, colcv);
    }

    k_pick_r14<<<(3 * BATCH * EMBED + 255) / 256, 256, 0, stream>>>(E, bu, bp, bn, fl, out, 0);

    for (int l = 0; l < 3; ++l) {
        if (use_csr) {
            k_gath_r14<<<(N_NODES + 3) / 4, 256, 0, stream>>>(rowptr, colcv, E, LE);
        } else {
            hipMemsetAsync(LE, 0, EB, stream);
            k_edge_r14<<<(NNZ + 3) / 4, 256, 0, stream>>>(edge_val, erow, ecol, fl, E, LE);
        }
        k_mlp_r14<<<768, 256, 0, stream>>>(E, LE, W1w, W1b, W2w, W2b, fl, l);
        k_pick_r14<<<(3 * BATCH * EMBED + 255) / 256, 256, 0, stream>>>(E, bu, bp, bn, fl, out, l + 1);
    }
}

// Round 5
// 964.837 us; speedup vs baseline: 8.4500x; 1.0565x over previous
//
#include <hip/hip_runtime.h>

#define NUM_USERS 50000
#define NUM_ITEMS 100000
#define N_NODES   150000
#define EMBED     64
#define BATCH     4096
#define NNZ       2400000
#define NB        586   // ceil(N_NODES/256)

__device__ __forceinline__ float bf2f(unsigned short u) {
    union { unsigned int u32; float f; } v; v.u32 = ((unsigned int)u) << 16; return v.f;
}
__device__ __forceinline__ float getf(const void* p, int i, int fbf) {
    if (fbf) return bf2f(((const unsigned short*)p)[i]);
    return ((const float*)p)[i];
}
__device__ __forceinline__ int geti(const void* p, int i, int i64) {
    if (i64) return (int)(((const long long*)p)[i]);
    return ((const int*)p)[i];
}
__device__ __forceinline__ int clampi(int v, int lo, int hi) {
    return v < lo ? lo : (v > hi ? hi : v);
}
__device__ __forceinline__ float rlanef(float v, int k) {
    return __int_as_float(__builtin_amdgcn_readlane(__float_as_int(v), k));
}
__device__ __forceinline__ int rlanei(int v, int k) {
    return __builtin_amdgcn_readlane(v, k);
}

// -------- dtype probes --------
__global__ void k_flags_r16(const unsigned short* __restrict__ ev,
                            const void* __restrict__ er, int* __restrict__ fl) {
    if (threadIdx.x == 0 && blockIdx.x == 0) {
        int good = 0;
        for (int i = 0; i < 64; ++i) {
            float f = bf2f(ev[i]);
            if (f >= 0.0f && f <= 0.011f) good++;
        }
        fl[0] = (good >= 60) ? 1 : 0;
        int ok = 0;
        for (int i = 0; i < 64; ++i) {
            long long v = ((const long long*)er)[i];
            if (v >= 0 && v < (long long)N_NODES) ok++;
        }
        fl[1] = (ok >= 60) ? 1 : 0;
    }
}

// -------- E0 = concat --------
__global__ void k_init_r16(const void* __restrict__ eu, const void* __restrict__ ei,
                           const int* __restrict__ fl, float* __restrict__ E) {
    int fbf = fl[0];
    int i = blockIdx.x * 256 + threadIdx.x;
    if (i < N_NODES * EMBED) {
        int r = i >> 6;
        float v;
        if (r < NUM_USERS) v = getf(eu, i, fbf);
        else               v = getf(ei, i - NUM_USERS * EMBED, fbf);
        E[i] = v;
    }
}

// ============ CSR build ============
__global__ __launch_bounds__(256) void k_count_r16(const void* __restrict__ er,
                                                   const int* __restrict__ fl,
                                                   int* __restrict__ cnt) {
    int e = blockIdx.x * 256 + threadIdx.x;
    if (e >= NNZ) return;
    int r = clampi(geti(er, e, fl[1]), 0, N_NODES - 1);
    atomicAdd(&cnt[r], 1);
}

__global__ __launch_bounds__(256) void k_scanA_r16(const int* __restrict__ cnt,
                                                   int* __restrict__ bsum) {
    int i = blockIdx.x * 256 + threadIdx.x;
    int v = (i < N_NODES) ? cnt[i] : 0;
    #pragma unroll
    for (int d = 1; d < 64; d <<= 1) v += __shfl_xor(v, d, 64);
    __shared__ int sh[4];
    if ((threadIdx.x & 63) == 0) sh[threadIdx.x >> 6] = v;
    __syncthreads();
    if (threadIdx.x == 0) bsum[blockIdx.x] = sh[0] + sh[1] + sh[2] + sh[3];
}

__global__ __launch_bounds__(1024) void k_scanB_r16(int* __restrict__ bsum) {
    __shared__ int sh[1024];
    int t = threadIdx.x;
    if (t < NB) sh[t] = bsum[t];
    __syncthreads();
    if (t == 0) {
        int run = 0;
        for (int i = 0; i < NB; ++i) { int x = sh[i]; sh[i] = run; run += x; }
    }
    __syncthreads();
    if (t < NB) bsum[t] = sh[t];
}

__global__ __launch_bounds__(256) void k_scanC_r16(const int* __restrict__ cnt,
                                                   const int* __restrict__ bsum,
                                                   int* __restrict__ rowptr) {
    __shared__ int sh[256];
    int i = blockIdx.x * 256 + threadIdx.x;
    int t = threadIdx.x;
    sh[t] = (i < N_NODES) ? cnt[i] : 0;
    __syncthreads();
    if (t == 0) {
        int run = bsum[blockIdx.x];
        for (int k = 0; k < 256; ++k) { int x = sh[k]; sh[k] = run; run += x; }
    }
    __syncthreads();
    if (i < N_NODES) rowptr[i] = sh[t];
    if (i == 0) rowptr[N_NODES] = NNZ;
}

// scatter edges into CSR slots — packed int2 {col, val_bits}
__global__ __launch_bounds__(256) void k_scatter_r16(const void* __restrict__ ev,
                                                     const void* __restrict__ er,
                                                     const void* __restrict__ ec,
                                                     const int* __restrict__ fl,
                                                     const int* __restrict__ rowptr,
                                                     int* __restrict__ cur,
                                                     int2* __restrict__ colcv) {
    int e = blockIdx.x * 256 + threadIdx.x;
    if (e >= NNZ) return;
    int i64 = fl[1], fbf = fl[0];
    int r = clampi(geti(er, e, i64), 0, N_NODES - 1);
    int c = clampi(geti(ec, e, i64), 0, N_NODES - 1);
    float v = getf(ev, e, fbf);
    int p = rowptr[r] + atomicAdd(&cur[r], 1);
    colcv[p] = make_int2(c, __float_as_int(v));
}

// ============ gather: LE[r] = sum val*E[col], wave/row, 8-deep load pipeline ============
__global__ __launch_bounds__(256) void k_gath_r16(const int* __restrict__ rowptr,
                                                  const int2* __restrict__ colcv,
                                                  const float* __restrict__ E,
                                                  float* __restrict__ LE) {
    int r = blockIdx.x * 4 + (threadIdx.x >> 6);
    if (r >= N_NODES) return;
    int lane = threadIdx.x & 63;
    int s = rowptr[r];
    int e = rowptr[r + 1];
    float acc = 0.0f;
    for (int base = s; base < e; base += 64) {
        int idx = base + lane;
        int2 cv = make_int2(0, 0);
        if (idx < e) cv = colcv[idx];
        int m = e - base; if (m > 64) m = 64;
        int j = 0;
        for (; j + 7 < m; j += 8) {
            int c0 = rlanei(cv.x, j + 0);
            int c1 = rlanei(cv.x, j + 1);
            int c2 = rlanei(cv.x, j + 2);
            int c3 = rlanei(cv.x, j + 3);
            int c4 = rlanei(cv.x, j + 4);
            int c5 = rlanei(cv.x, j + 5);
            int c6 = rlanei(cv.x, j + 6);
            int c7 = rlanei(cv.x, j + 7);
            float p0 = E[c0 * EMBED + lane];
            float p1 = E[c1 * EMBED + lane];
            float p2 = E[c2 * EMBED + lane];
            float p3 = E[c3 * EMBED + lane];
            float p4 = E[c4 * EMBED + lane];
            float p5 = E[c5 * EMBED + lane];
            float p6 = E[c6 * EMBED + lane];
            float p7 = E[c7 * EMBED + lane];
            acc = fmaf(__int_as_float(rlanei(cv.y, j + 0)), p0, acc);
            acc = fmaf(__int_as_float(rlanei(cv.y, j + 1)), p1, acc);
            acc = fmaf(__int_as_float(rlanei(cv.y, j + 2)), p2, acc);
            acc = fmaf(__int_as_float(rlanei(cv.y, j + 3)), p3, acc);
            acc = fmaf(__int_as_float(rlanei(cv.y, j + 4)), p4, acc);
            acc = fmaf(__int_as_float(rlanei(cv.y, j + 5)), p5, acc);
            acc = fmaf(__int_as_float(rlanei(cv.y, j + 6)), p6, acc);
            acc = fmaf(__int_as_float(rlanei(cv.y, j + 7)), p7, acc);
        }
        for (; j + 3 < m; j += 4) {
            int c0 = rlanei(cv.x, j + 0);
            int c1 = rlanei(cv.x, j + 1);
            int c2 = rlanei(cv.x, j + 2);
            int c3 = rlanei(cv.x, j + 3);
            float p0 = E[c0 * EMBED + lane];
            float p1 = E[c1 * EMBED + lane];
            float p2 = E[c2 * EMBED + lane];
            float p3 = E[c3 * EMBED + lane];
            acc = fmaf(__int_as_float(rlanei(cv.y, j + 0)), p0, acc);
            acc = fmaf(__int_as_float(rlanei(cv.y, j + 1)), p1, acc);
            acc = fmaf(__int_as_float(rlanei(cv.y, j + 2)), p2, acc);
            acc = fmaf(__int_as_float(rlanei(cv.y, j + 3)), p3, acc);
        }
        for (; j < m; ++j) {
            int cj = rlanei(cv.x, j);
            float vj = __int_as_float(rlanei(cv.y, j));
            acc = fmaf(vj, E[cj * EMBED + lane], acc);
        }
    }
    LE[r * EMBED + lane] = acc;
}

// -------- fallback atomic edge pass (small-ws path) --------
__global__ __launch_bounds__(256) void k_edge_r16(const void* __restrict__ ev,
                                                  const void* __restrict__ er,
                                                  const void* __restrict__ ec,
                                                  const int* __restrict__ fl,
                                                  const float* __restrict__ E,
                                                  float* __restrict__ LE) {
    int fbf = fl[0];
    int i64 = fl[1];
    int e = blockIdx.x * 4 + (threadIdx.x >> 6);
    int lane = threadIdx.x & 63;
    if (e >= NNZ) return;
    int r = clampi(geti(er, e, i64), 0, N_NODES - 1);
    int c = clampi(geti(ec, e, i64), 0, N_NODES - 1);
    float v = getf(ev, e, fbf);
    atomicAdd(&LE[r * EMBED + lane], v * E[c * EMBED + lane]);
}

// -------- dense layer: wave-per-row, weights in regs, x broadcast via LDS b128 --------
// Identity: (LE+E)@W1^T + LE@W2^T + b = LE@(W1+W2)^T + E@W1^T + b
// Staging: XA = LE   (pairs with w12r = W1+W2 row)
//          XB = E    (pairs with w1r  = W1 row)        <-- r15 had these crossed
__global__ __launch_bounds__(256) void k_mlp_r16(float* __restrict__ E,
                                                 const float* __restrict__ LE,
                                                 const void* __restrict__ W1,
                                                 const void* __restrict__ B1,
                                                 const void* __restrict__ W2,
                                                 const void* __restrict__ B2,
                                                 const int* __restrict__ fl, int layer) {
    __shared__ float4 XA[4][16];   // per-wave slot: LE (64 floats)
    __shared__ float4 XB[4][16];   // per-wave slot: E
    const int fbf  = fl[0];
    const int wofs = layer * EMBED * EMBED;
    const int bofs = layer * EMBED;
    const int lane = threadIdx.x & 63;
    const int w    = threadIdx.x >> 6;

    // per-thread weight registers: w1r[k] = W1[lane,k]; w12r[k] = W1[lane,k]+W2[lane,k]
    float w1r[64], w12r[64];
    if (fbf) {
        const unsigned short* p1 = (const unsigned short*)W1 + wofs + lane * 64;
        const unsigned short* p2 = (const unsigned short*)W2 + wofs + lane * 64;
        #pragma unroll
        for (int q = 0; q < 16; ++q) {
            ushort4 a = reinterpret_cast<const ushort4*>(p1)[q];
            ushort4 b = reinterpret_cast<const ushort4*>(p2)[q];
            float f0 = bf2f(a.x), f1 = bf2f(a.y), f2 = bf2f(a.z), f3 = bf2f(a.w);
            w1r[4*q+0] = f0; w1r[4*q+1] = f1; w1r[4*q+2] = f2; w1r[4*q+3] = f3;
            w12r[4*q+0] = f0 + bf2f(b.x); w12r[4*q+1] = f1 + bf2f(b.y);
            w12r[4*q+2] = f2 + bf2f(b.z); w12r[4*q+3] = f3 + bf2f(b.w);
        }
    } else {
        const float* p1 = (const float*)W1 + wofs + lane * 64;
        const float* p2 = (const float*)W2 + wofs + lane * 64;
        #pragma unroll
        for (int q = 0; q < 16; ++q) {
            float4 a = reinterpret_cast<const float4*>(p1)[q];
            float4 b = reinterpret_cast<const float4*>(p2)[q];
            w1r[4*q+0] = a.x; w1r[4*q+1] = a.y; w1r[4*q+2] = a.z; w1r[4*q+3] = a.w;
            w12r[4*q+0] = a.x + b.x; w12r[4*q+1] = a.y + b.y;
            w12r[4*q+2] = a.z + b.z; w12r[4*q+3] = a.w + b.w;
        }
    }
    const float bias = getf(B1, bofs + lane, fbf) + getf(B2, bofs + lane, fbf);

    const int gw = blockIdx.x * 4 + w;
    const int nw = gridDim.x * 4;

    int row = gw;
    float le = 0.0f, ee = 0.0f;
    if (row < N_NODES) {
        le = LE[row * EMBED + lane];
        ee = E[row * EMBED + lane];
    }
    while (row < N_NODES) {
        const int nrow = row + nw;
        float nle = 0.0f, nee = 0.0f;
        if (nrow < N_NODES) {
            nle = LE[nrow * EMBED + lane];
            nee = E[nrow * EMBED + lane];
        }

        // stage this row's x into the wave's private LDS slot (broadcast source)
        ((float*)&XA[w][0])[lane] = le;   // LE  -> w12r
        ((float*)&XB[w][0])[lane] = ee;   // E   -> w1r
        float acc0 = bias, acc1 = 0.0f;
        #pragma unroll
        for (int q = 0; q < 16; ++q) {
            float4 a = XA[w][q];   // wave-uniform ds_read_b128 broadcast
            float4 b = XB[w][q];
            acc0 = fmaf(a.x, w12r[4*q+0], acc0);
            acc1 = fmaf(b.x, w1r [4*q+0], acc1);
            acc0 = fmaf(a.y, w12r[4*q+1], acc0);
            acc1 = fmaf(b.y, w1r [4*q+1], acc1);
            acc0 = fmaf(a.z, w12r[4*q+2], acc0);
            acc1 = fmaf(b.z, w1r [4*q+2], acc1);
            acc0 = fmaf(a.w, w12r[4*q+3], acc0);
            acc1 = fmaf(b.w, w1r [4*q+3], acc1);
        }
        float acc = acc0 + acc1;
        float h = (acc > 0.0f) ? acc : 0.2f * acc;

        float s = h * h;
        #pragma unroll
        for (int d = 1; d < 64; d <<= 1) s += __shfl_xor(s, d, 64);
        const float inv = 1.0f / fmaxf(sqrtf(s), 1e-12f);

        E[row * EMBED + lane] = h * inv;

        row = nrow; le = nle; ee = nee;
    }
}

// -------- gather batch rows into output --------
__global__ void k_pick_r16(const float* __restrict__ E, const void* __restrict__ bu,
                           const void* __restrict__ bp, const void* __restrict__ bn,
                           const int* __restrict__ fl,
                           float* __restrict__ out, int stage) {
    int i64 = fl[1];
    int i = blockIdx.x * 256 + threadIdx.x;
    if (i >= 3 * BATCH * EMBED) return;
    int c = i & 63;
    int row = i >> 6;
    int o = row >> 12;
    int b = row & 4095;
    int idx;
    if (o == 0)      idx = geti(bu, b, i64);
    else if (o == 1) idx = geti(bp, b, i64);
    else             idx = geti(bn, b, i64);
    int src;
    if (o == 0) src = clampi(idx, 0, NUM_USERS - 1);
    else        src = NUM_USERS + clampi(idx, 0, NUM_ITEMS - 1);
    int pos = o * (BATCH * 256) + b * 256 + stage * 64 + c;
    out[pos] = E[src * EMBED + c];
}

// -------- launch --------
extern "C" void kernel_launch(void* const* d_in, const int* in_sizes, int n_in,
                              void* d_out, int out_size, void* d_ws, size_t ws_size,
                              hipStream_t stream) {
    const void* edge_val = d_in[0];
    const void* emb_u    = d_in[1];
    const void* emb_i    = d_in[2];
    const void* W1w      = d_in[3];
    const void* W1b      = d_in[4];
    const void* W2w      = d_in[5];
    const void* W2b      = d_in[6];
    const void* erow     = d_in[7];
    const void* ecol     = d_in[8];
    const void* bu       = d_in[9];
    const void* bp       = d_in[10];
    const void* bn       = d_in[11];

    const size_t EB   = (size_t)N_NODES * EMBED * sizeof(float);   // 38.4 MB
    const size_t RPB  = 600064;                                     // rowptr
    const size_t CNB  = 600064;                                     // cnt/cursor
    const size_t BSB  = 4096;                                       // block sums
    const size_t CVB2 = (size_t)NNZ * sizeof(int2);                 // 19.2 MB packed (c,v)

    const size_t need_old = 256 + 2 * EB;
    const size_t need_csr = 256 + 2 * EB + RPB + CNB + BSB + CVB2;
    if (ws_size < need_old) return;   // zero-output signature

    char* ws = (char*)d_ws;
    int*   fl     = (int*)ws;
    float* E      = (float*)(ws + 256);
    float* LE     = (float*)(ws + 256 + EB);
    int*   rowptr = (int*)(ws + 256 + 2 * EB);
    int*   cnt    = (int*)(ws + 256 + 2 * EB + RPB);
    int*   bsum   = (int*)(ws + 256 + 2 * EB + RPB + CNB);
    int2*  colcv  = (int2*)(ws + 256 + 2 * EB + RPB + CNB + BSB);
    float* out    = (float*)d_out;

    const bool use_csr = (ws_size >= need_csr);

    k_flags_r16<<<1, 64, 0, stream>>>((const unsigned short*)edge_val, erow, fl);

    k_init_r16<<<(N_NODES * EMBED + 255) / 256, 256, 0, stream>>>(emb_u, emb_i, fl, E);

    if (use_csr) {
        hipMemsetAsync(cnt, 0, CNB, stream);
        k_count_r16<<<(NNZ + 255) / 256, 256, 0, stream>>>(erow, fl, cnt);
        k_scanA_r16<<<NB, 256, 0, stream>>>(cnt, bsum);
        k_scanB_r16<<<1, 1024, 0, stream>>>(bsum);
        k_scanC_r16<<<NB, 256, 0, stream>>>(cnt, bsum, rowptr);
        hipMemsetAsync(cnt, 0, CNB, stream);
        k_scatter_r16<<<(NNZ + 255) / 256, 256, 0, stream>>>(edge_val, erow, ecol, fl,
                                                             rowptr, cnt, colcv);
    }

    k_pick_r16<<<(3 * BATCH * EMBED + 255) / 256, 256, 0, stream>>>(E, bu, bp, bn, fl, out, 0);

    for (int l = 0; l < 3; ++l) {
        if (use_csr) {
            k_gath_r16<<<(N_NODES + 3) / 4, 256, 0, stream>>>(rowptr, colcv, E, LE);
        } else {
            hipMemsetAsync(LE, 0, EB, stream);
            k_edge_r16<<<(NNZ + 3) / 4, 256, 0, stream>>>(edge_val, erow, ecol, fl, E, LE);
        }
        k_mlp_r16<<<1280, 256, 0, stream>>>(E, LE, W1w, W1b, W2w, W2b, fl, l);
        k_pick_r16<<<(3 * BATCH * EMBED + 255) / 256, 256, 0, stream>>>(E, bu, bp, bn, fl, out, l + 1);
    }
}